// Round 4
// baseline (39.642 us; speedup 1.0000x reference)
//
#include <hip/hip_runtime.h>
#include <hip/hip_bf16.h>

// loss = mean_b (out_b - label_b)^2
// out_b = sqrt(s_ab) / (s_aa^(1/4) * s_bb^(1/4))
// Gram identity: ||X Y^T||_F^2 = <X^T X, Y^T Y>  so with
//   G_A = A^T A, G_B = B^T B (384x384, K=256):
//   s_aa = ||G_A||_F^2, s_bb = ||G_B||_F^2, s_ab = <G_A, G_B>.
// One WG = one 128x128 site (I,J) of G, computing tiles of BOTH grams;
// per-wave 64x64 quadrant; all three reductions are elementwise on the
// two accumulators (layout-agnostic: identical frag sourcing => identical
// C/D layouts => correct pairing; sums are permutation-invariant).

typedef short short8 __attribute__((ext_vector_type(8)));
typedef float f32x4  __attribute__((ext_vector_type(4)));

constexpr int BATCH = 128;
constexpr int S  = 256;      // rows of A/B = contraction dim of the gram
constexpr int D  = 384;      // cols of A/B = gram dim
constexpr int KC = 32;       // K-chunk (rows staged per iteration)
constexpr int NCH = S / KC;  // 8

__device__ const signed char SI[6] = {0,0,0,1,1,2};
__device__ const signed char SJ[6] = {0,1,2,1,2,2};

__device__ __forceinline__ short bf16_of(float f){
    __hip_bfloat16 h = __float2bfloat16(f);   // RNE
    short s; __builtin_memcpy(&s, &h, 2); return s;
}

// LDS: transposed store, [col cc 0..511][32 rows] bf16, 16B chunk per
// (cc, r8). Swizzle puts frag ds_read_b128 at the bank floor and spreads
// stage writes: halfword offset of chunk (cc, r8):
__device__ __forceinline__ int ch_off(int cc, int r8){
    return cc*32 + ((((cc>>1) + (cc>>4) + r8) & 3) << 3);
}

#define MFMA16(a,b,c) __builtin_amdgcn_mfma_f32_16x16x32_bf16(a,b,c,0,0,0)

__global__ __launch_bounds__(256, 2)
void gram(const float* __restrict__ A, const float* __restrict__ B,
          float* __restrict__ ws)
{
    __shared__ short lds[2][512*32];   // 2 x 32 KiB double buffer

    // bid -> (batch, site); all 6 sites of a batch share an XCD (bid&7).
    const int bid = blockIdx.x;
    const int g   = bid >> 3;
    const int b   = (bid & 7) + ((g / 6) << 3);
    const int s   = g % 6;
    const int I = SI[s], J = SJ[s];
    const float w = (I == J) ? 1.0f : 2.0f;   // off-diag sites count twice

    const size_t mb = (size_t)b * S * D;
    const float* __restrict__ base0 = A + mb;
    const float* __restrict__ base1 = B + mb;

    const int tid  = threadIdx.x;
    const int lane = tid & 63;
    const int wv   = tid >> 6;

    // ---- staging map: thread -> (col-quad u, 8-row group z) ----
    const int u = lane;                         // 0..63 (32 quads per side)
    const int z = wv;                           // 0..3
    const int colg = ((u >> 5) ? J : I) * 128 + 4*(u & 31);
    const float* __restrict__ g0 = base0 + (size_t)z*8*D + colg;
    const float* __restrict__ g1 = base1 + (size_t)z*8*D + colg;

    int wo0[4], wo1[4];
    #pragma unroll
    for (int i = 0; i < 4; ++i) {
        wo0[i] = ch_off(      4*u + i, z);      // mat0 cols 0..255
        wo1[i] = ch_off(256 + 4*u + i, z);      // mat1 cols 256..511
    }

    // ---- wave -> 64x64 quadrant (diag site: dup the off-diag quadrant) ----
    int xq, yq;
    if (I == J) { xq = (wv == 3); yq = (wv != 0); }  // (0,0),(0,1),(0,1),(1,1)
    else        { xq = wv >> 1;   yq = wv & 1;    }
    const int xoff = xq * 64, yoff = yq * 64;

    int roA[2][4], roB[2][4];
    #pragma unroll
    for (int m = 0; m < 2; ++m)
      #pragma unroll
      for (int q = 0; q < 4; ++q) {
        roA[m][q] = ch_off(m*256 +       xoff + q*16 + (lane & 15), lane >> 4);
        roB[m][q] = ch_off(m*256 + 128 + yoff + q*16 + (lane & 15), lane >> 4);
      }

    f32x4 acc[2][16] = {};   // [mat][4x4 of 16x16 tiles], 128 VGPR
    f32x4 v0[8], v1[8];      // in-flight K-chunk (rows z*8..z*8+7, 4 cols)

#define LOADS(kc) { \
    const float* p0 = g0 + (size_t)(kc)*KC*D; \
    const float* p1 = g1 + (size_t)(kc)*KC*D; \
    _Pragma("unroll") for (int rr = 0; rr < 8; ++rr) { \
        v0[rr] = *(const f32x4*)(p0 + rr*D); \
        v1[rr] = *(const f32x4*)(p1 + rr*D); } }

// register-transpose: 8 rows x 4 cols -> per-col short8, swizzled b128 write
#define WRITES(bsel) { \
    _Pragma("unroll") for (int i = 0; i < 4; ++i) { \
        short8 q0, q1; \
        _Pragma("unroll") for (int rr = 0; rr < 8; ++rr) { \
            q0[rr] = bf16_of(v0[rr][i]); q1[rr] = bf16_of(v1[rr][i]); } \
        *(short8*)&lds[bsel][wo0[i]] = q0; \
        *(short8*)&lds[bsel][wo1[i]] = q1; } }

#define COMPUTE(bsel) { \
    _Pragma("unroll") for (int m = 0; m < 2; ++m) { \
        short8 af[4], bq[4]; \
        _Pragma("unroll") for (int q = 0; q < 4; ++q) { \
            af[q] = *(const short8*)&lds[bsel][roA[m][q]]; \
            bq[q] = *(const short8*)&lds[bsel][roB[m][q]]; } \
        _Pragma("unroll") for (int mi = 0; mi < 4; ++mi) \
          _Pragma("unroll") for (int ni = 0; ni < 4; ++ni) \
            acc[m][mi*4+ni] = MFMA16(af[mi], bq[ni], acc[m][mi*4+ni]); } }

    // ---- main loop: issue next chunk's loads early (T14), dbuf LDS ----
    LOADS(0); WRITES(0); __syncthreads();
    for (int c = 0; c < NCH; ++c) {
        if (c + 1 < NCH) LOADS(c + 1);
        COMPUTE(c & 1);
        if (c + 1 < NCH) WRITES((c + 1) & 1);
        __syncthreads();
    }

    // ---- three reductions, elementwise on the paired accumulators ----
    float saa = 0.f, sbb = 0.f, sab = 0.f;
    #pragma unroll
    for (int q = 0; q < 16; ++q)
      #pragma unroll
      for (int e = 0; e < 4; ++e) {
        const float a = acc[0][q][e], bb = acc[1][q][e];
        saa += a*a; sbb += bb*bb; sab += a*bb;
      }
    saa *= w; sbb *= w; sab *= w;
    #pragma unroll
    for (int o = 32; o > 0; o >>= 1) {
        saa += __shfl_xor(saa, o, 64);
        sbb += __shfl_xor(sbb, o, 64);
        sab += __shfl_xor(sab, o, 64);
    }
    float* red = (float*)lds;
    if (lane == 0) { red[wv*3+0]=saa; red[wv*3+1]=sbb; red[wv*3+2]=sab; }
    __syncthreads();
    if (tid == 0) {
        float t0=0.f, t1=0.f, t2=0.f;
        #pragma unroll
        for (int k = 0; k < 4; ++k) {
            t0 += red[k*3+0]; t1 += red[k*3+1]; t2 += red[k*3+2];
        }
        ws[bid*4+0]=t0; ws[bid*4+1]=t1; ws[bid*4+2]=t2;
    }
}

__global__ void finalize(const float* __restrict__ ws,
                         const float* __restrict__ labels,
                         float* __restrict__ out)
{
    __shared__ float red[128];
    const int b = threadIdx.x;                  // one thread per batch
    float saa=0.f, sbb=0.f, sab=0.f;
    #pragma unroll
    for (int s = 0; s < 6; ++s) {
        const int wg = (((b >> 3) * 6 + s) << 3) + (b & 7);
        saa += ws[wg*4+0]; sbb += ws[wg*4+1]; sab += ws[wg*4+2];
    }
    const float outb = sqrtf(sab) / (sqrtf(sqrtf(saa)) * sqrtf(sqrtf(sbb)));
    const float d    = outb - labels[b];
    red[b] = d * d * (1.0f / 128.0f);
    __syncthreads();
    for (int off = 64; off > 0; off >>= 1) {
        if (b < off) red[b] += red[b + off];
        __syncthreads();
    }
    if (b == 0) out[0] = red[0];
}

extern "C" void kernel_launch(void* const* d_in, const int* in_sizes, int n_in,
                              void* d_out, int out_size, void* d_ws, size_t ws_size,
                              hipStream_t stream)
{
    const float* A      = (const float*)d_in[0];
    const float* B      = (const float*)d_in[1];
    const float* labels = (const float*)d_in[2];
    float* ws = (float*)d_ws;   // 768*4 floats, all slots written every launch

    gram<<<dim3(BATCH * 6), dim3(256), 0, stream>>>(A, B, ws);
    finalize<<<dim3(1), dim3(128), 0, stream>>>(ws, labels, (float*)d_out);
}